// Round 2
// baseline (594.786 us; speedup 1.0000x reference)
//
#include <hip/hip_runtime.h>

// RelGraphConv basis-decomposition forward, MI355X.
// Pipeline:
//   k1: hb2[n, col, b] = feat[n] @ V_b (interleaved float2 per col), and
//       out[n] = feat[n] @ loop_w + bias          (self-loop baseline)
//   CSR build by dst: memset -> hist -> 1-block scan -> scatter(pack src|et<<17)
//   k_gather: one wave per dst node, lane = out feature, register accumulate,
//       out[n][lane] += sum_e c0*hb[src,0,lane] + c1*hb[src,1,lane]

constexpr int N_NODES  = 100000;
constexpr int N_EDGES  = 1600000;
constexpr int IN_FEAT  = 64;
constexpr int OUT_FEAT = 64;

constexpr int K1_COLS = 192;   // 128 hb columns (2 bases x 64) + 64 loop columns
constexpr int K1_NB   = 8;     // nodes per block-iteration

// ---------------------------------------------------------------- kernel 1
// thread t < 128 : computes hb[n, b=t>>6, col=t&63], stored interleaved:
//                  hb2[n*128 + col*2 + b]
// thread t >= 128: out[n, t-128] = feat[n]·loop_w[:,t-128] + bias
// Per-thread weight column held in 64 VGPRs (loaded coalesced, wave-aligned).
__global__ __launch_bounds__(K1_COLS) void k1_node_transform(
    const float* __restrict__ feat,        // (N, 64)
    const float* __restrict__ weight,      // (2, 64, 64)
    const float* __restrict__ loop_weight, // (64, 64)
    const float* __restrict__ h_bias,      // (64,)
    float* __restrict__ hb2,               // (N, 64, 2)  [ws]
    float* __restrict__ out)               // (N, 64)
{
    __shared__ float Fl[K1_NB][IN_FEAT];
    const int tid = threadIdx.x;
    const int col = tid & 63;

    // Load this thread's weight column into registers. Within each wave the
    // 64 lanes read consecutive addresses at each i -> fully coalesced.
    float w[IN_FEAT];
    #pragma unroll
    for (int i = 0; i < IN_FEAT; ++i) {
        if (tid < 128) w[i] = weight[(tid >> 6) * (IN_FEAT * OUT_FEAT) + i * OUT_FEAT + col];
        else           w[i] = loop_weight[i * OUT_FEAT + col];
    }
    const float bias = (tid >= 128) ? h_bias[col] : 0.0f;

    for (int base = blockIdx.x * K1_NB; base < N_NODES; base += gridDim.x * K1_NB) {
        __syncthreads();  // protect Fl reuse across iterations
        for (int idx = tid; idx < K1_NB * IN_FEAT; idx += K1_COLS) {
            const int j = idx >> 6, i = idx & 63;
            const int n = base + j;
            Fl[j][i] = (n < N_NODES) ? feat[n * IN_FEAT + i] : 0.0f;
        }
        __syncthreads();
        #pragma unroll 1
        for (int j = 0; j < K1_NB; ++j) {
            const int n = base + j;
            if (n >= N_NODES) break;
            const float4* f4 = (const float4*)Fl[j];
            float acc = 0.0f;
            #pragma unroll
            for (int i4 = 0; i4 < IN_FEAT / 4; ++i4) {
                const float4 f = f4[i4];      // uniform address -> LDS broadcast
                acc = fmaf(f.x, w[4 * i4 + 0], acc);
                acc = fmaf(f.y, w[4 * i4 + 1], acc);
                acc = fmaf(f.z, w[4 * i4 + 2], acc);
                acc = fmaf(f.w, w[4 * i4 + 3], acc);
            }
            if (tid < 128) hb2[(size_t)n * 128 + col * 2 + (tid >> 6)] = acc;
            else           out[(size_t)n * OUT_FEAT + col] = acc + bias;
        }
    }
}

// ---------------------------------------------------------------- CSR build
__global__ __launch_bounds__(256) void k_hist(const int* __restrict__ dst,
                                              int* __restrict__ cnt) {
    const int e = blockIdx.x * 256 + threadIdx.x;
    if (e < N_EDGES) atomicAdd(&cnt[dst[e]], 1);
}

// Single-block exclusive scan over N_NODES counts.
// cnt_cur: in = counts, out = running offset (becomes the scatter cursor).
// offsets: exclusive prefix, N_NODES+1 entries.
__global__ __launch_bounds__(1024) void k_scan(int* cnt_cur, int* offsets) {
    __shared__ int part[1024];
    const int t = threadIdx.x;
    constexpr int CHUNK = (N_NODES + 1023) / 1024;  // 98
    const int begin = t * CHUNK;
    const int stop  = (begin + CHUNK < N_NODES) ? begin + CHUNK : N_NODES;
    int s = 0;
    for (int i = begin; i < stop; ++i) s += cnt_cur[i];
    part[t] = s;
    __syncthreads();
    // Hillis-Steele inclusive scan over 1024 partials
    for (int d = 1; d < 1024; d <<= 1) {
        const int v = (t >= d) ? part[t - d] : 0;
        __syncthreads();
        part[t] += v;
        __syncthreads();
    }
    int run = (t == 0) ? 0 : part[t - 1];
    for (int i = begin; i < stop; ++i) {
        const int c = cnt_cur[i];
        offsets[i] = run;
        cnt_cur[i] = run;   // cursor for scatter
        run += c;
    }
    if (t == 1023) offsets[N_NODES] = part[1023];
}

__global__ __launch_bounds__(256) void k_scatter(const int* __restrict__ src,
                                                 const int* __restrict__ dst,
                                                 const int* __restrict__ et,
                                                 int* __restrict__ cursor,
                                                 unsigned* __restrict__ sorted) {
    const int e = blockIdx.x * 256 + threadIdx.x;
    if (e < N_EDGES) {
        const int pos = atomicAdd(&cursor[dst[e]], 1);
        sorted[pos] = (unsigned)src[e] | ((unsigned)et[e] << 17);  // src < 2^17, et < 64
    }
}

// ---------------------------------------------------------------- gather
// One 64-lane wave per dst node; lane = output feature.
__global__ __launch_bounds__(256) void k_gather(
    const int*      __restrict__ offsets,
    const unsigned* __restrict__ sorted,
    const float*    __restrict__ w_comp,   // (64, 2)
    const float*    __restrict__ hb2,      // (N, 64, 2)
    float*          __restrict__ out)      // (N, 64)
{
    const int lane = threadIdx.x & 63;
    int n = blockIdx.x * 4 + (threadIdx.x >> 6);
    if (n >= N_NODES) return;
    n = __builtin_amdgcn_readfirstlane(n);

    const int start = __builtin_amdgcn_readfirstlane(offsets[n]);
    const int end   = __builtin_amdgcn_readfirstlane(offsets[n + 1]);
    const float2* __restrict__ wc2  = (const float2*)w_comp;
    const float2* __restrict__ hb2v = (const float2*)hb2;

    float acc = 0.0f;
    int k = start;
    for (; k + 1 < end; k += 2) {
        const unsigned p0 = sorted[k], p1 = sorted[k + 1];
        const int s0 = p0 & 0x1FFFF, r0 = p0 >> 17;
        const int s1 = p1 & 0x1FFFF, r1 = p1 >> 17;
        const float2 c0 = wc2[r0];
        const float2 c1 = wc2[r1];
        const float2 h0 = hb2v[(size_t)s0 * 64 + lane];  // 512B/wave, contiguous
        const float2 h1 = hb2v[(size_t)s1 * 64 + lane];
        acc = fmaf(c0.x, h0.x, acc);
        acc = fmaf(c0.y, h0.y, acc);
        acc = fmaf(c1.x, h1.x, acc);
        acc = fmaf(c1.y, h1.y, acc);
    }
    if (k < end) {
        const unsigned p0 = sorted[k];
        const int s0 = p0 & 0x1FFFF, r0 = p0 >> 17;
        const float2 c0 = wc2[r0];
        const float2 h0 = hb2v[(size_t)s0 * 64 + lane];
        acc = fmaf(c0.x, h0.x, acc);
        acc = fmaf(c0.y, h0.y, acc);
    }
    out[(size_t)n * OUT_FEAT + lane] += acc;   // single writer, non-atomic
}

// ---------------------------------------------------------------- launch
extern "C" void kernel_launch(void* const* d_in, const int* in_sizes, int n_in,
                              void* d_out, int out_size, void* d_ws, size_t ws_size,
                              hipStream_t stream) {
    const float* feat        = (const float*)d_in[0];
    const float* weight      = (const float*)d_in[1];
    const float* w_comp      = (const float*)d_in[2];
    const float* loop_weight = (const float*)d_in[3];
    const float* h_bias      = (const float*)d_in[4];
    const int*   src         = (const int*)d_in[5];
    const int*   dst         = (const int*)d_in[6];
    const int*   etypes      = (const int*)d_in[7];
    float* out = (float*)d_out;

    // ws layout (4-byte units): hb2 | offsets | cursor | sorted  = 58.4 MB
    float*    hb2     = (float*)d_ws;                       // 12,800,000 f32
    int*      offsets = (int*)d_ws + 12800000;              // 100,001 i32
    int*      cursor  = offsets + (N_NODES + 1);            // 100,000 i32
    unsigned* sorted  = (unsigned*)(cursor + N_NODES);      // 1,600,000 u32

    hipMemsetAsync(cursor, 0, (size_t)N_NODES * sizeof(int), stream);
    k_hist<<<(N_EDGES + 255) / 256, 256, 0, stream>>>(dst, cursor);
    k_scan<<<1, 1024, 0, stream>>>(cursor, offsets);
    k1_node_transform<<<2048, K1_COLS, 0, stream>>>(feat, weight, loop_weight, h_bias, hb2, out);
    k_scatter<<<(N_EDGES + 255) / 256, 256, 0, stream>>>(src, dst, etypes, cursor, sorted);
    k_gather<<<(N_NODES + 3) / 4, 256, 0, stream>>>(offsets, sorted, w_comp, hb2, out);
}

// Round 3
// 392.667 us; speedup vs baseline: 1.5147x; 1.5147x over previous
//
#include <hip/hip_runtime.h>

// RelGraphConv basis-decomposition forward, MI355X.
// Pipeline:
//   k1: hb2[n, col, {b0,b1}] = feat[n] @ V_b (interleaved float2 per col), and
//       out[n] = feat[n] @ loop_w + bias          (self-loop baseline)
//   CSR build by dst: memset -> hist -> 3-phase multi-block scan -> scatter
//   k_gather: one wave per dst node, lane = out feature, register accumulate,
//       out[n][lane] += sum_e c0*hb[src,0,lane] + c1*hb[src,1,lane]

constexpr int N_NODES  = 100000;
constexpr int N_EDGES  = 1600000;
constexpr int IN_FEAT  = 64;
constexpr int OUT_FEAT = 64;

constexpr int K1_COLS = 192;   // 128 hb columns (2 bases x 64) + 64 loop columns
constexpr int K1_NB   = 8;     // nodes per block-iteration

constexpr int SCAN_BLK = 256;
constexpr int N_SCAN_BLOCKS = (N_NODES + SCAN_BLK - 1) / SCAN_BLK;  // 391

// ---------------------------------------------------------------- kernel 1
__global__ __launch_bounds__(K1_COLS) void k1_node_transform(
    const float* __restrict__ feat,        // (N, 64)
    const float* __restrict__ weight,      // (2, 64, 64)
    const float* __restrict__ loop_weight, // (64, 64)
    const float* __restrict__ h_bias,      // (64,)
    float* __restrict__ hb2,               // (N, 64, 2)  [ws]
    float* __restrict__ out)               // (N, 64)
{
    __shared__ float Fl[K1_NB][IN_FEAT];
    const int tid = threadIdx.x;
    const int col = tid & 63;

    // This thread's weight column in registers; coalesced across each wave.
    float w[IN_FEAT];
    #pragma unroll
    for (int i = 0; i < IN_FEAT; ++i) {
        if (tid < 128) w[i] = weight[(tid >> 6) * (IN_FEAT * OUT_FEAT) + i * OUT_FEAT + col];
        else           w[i] = loop_weight[i * OUT_FEAT + col];
    }
    const float bias = (tid >= 128) ? h_bias[col] : 0.0f;

    for (int base = blockIdx.x * K1_NB; base < N_NODES; base += gridDim.x * K1_NB) {
        __syncthreads();  // protect Fl reuse across iterations
        for (int idx = tid; idx < K1_NB * IN_FEAT; idx += K1_COLS) {
            const int j = idx >> 6, i = idx & 63;
            const int n = base + j;
            Fl[j][i] = (n < N_NODES) ? feat[n * IN_FEAT + i] : 0.0f;
        }
        __syncthreads();
        #pragma unroll 1
        for (int j = 0; j < K1_NB; ++j) {
            const int n = base + j;
            if (n >= N_NODES) break;
            const float4* f4 = (const float4*)Fl[j];
            // 4 partial accumulators: breaks the 64-deep dependent fmaf chain.
            float a0 = 0.f, a1 = 0.f, a2 = 0.f, a3 = 0.f;
            #pragma unroll
            for (int i4 = 0; i4 < IN_FEAT / 4; ++i4) {
                const float4 f = f4[i4];      // uniform address -> LDS broadcast
                a0 = fmaf(f.x, w[4 * i4 + 0], a0);
                a1 = fmaf(f.y, w[4 * i4 + 1], a1);
                a2 = fmaf(f.z, w[4 * i4 + 2], a2);
                a3 = fmaf(f.w, w[4 * i4 + 3], a3);
            }
            const float acc = (a0 + a1) + (a2 + a3);
            if (tid < 128) hb2[(size_t)n * 128 + col * 2 + (tid >> 6)] = acc;
            else           out[(size_t)n * OUT_FEAT + col] = acc + bias;
        }
    }
}

// ---------------------------------------------------------------- CSR build
__global__ __launch_bounds__(256) void k_hist(const int* __restrict__ dst,
                                              int* __restrict__ cnt) {
    const int e = blockIdx.x * 256 + threadIdx.x;
    if (e < N_EDGES) atomicAdd(&cnt[dst[e]], 1);
}

// Phase A: per-block sums of counts.
__global__ __launch_bounds__(SCAN_BLK) void k_scan_a(const int* __restrict__ cnt,
                                                     int* __restrict__ bsum) {
    __shared__ int red[SCAN_BLK / 64];
    const int i = blockIdx.x * SCAN_BLK + threadIdx.x;
    int v = (i < N_NODES) ? cnt[i] : 0;
    #pragma unroll
    for (int d = 1; d < 64; d <<= 1) v += __shfl_xor(v, d);
    if ((threadIdx.x & 63) == 0) red[threadIdx.x >> 6] = v;
    __syncthreads();
    if (threadIdx.x == 0) {
        int s = 0;
        #pragma unroll
        for (int wv = 0; wv < SCAN_BLK / 64; ++wv) s += red[wv];
        bsum[blockIdx.x] = s;
    }
}

// Phase B: one block scans the 391 block sums -> exclusive block offsets.
__global__ __launch_bounds__(512) void k_scan_b(int* __restrict__ bsum) {
    __shared__ int part[512];
    const int t = threadIdx.x;
    const int v = (t < N_SCAN_BLOCKS) ? bsum[t] : 0;
    part[t] = v;
    __syncthreads();
    for (int d = 1; d < 512; d <<= 1) {
        const int u = (t >= d) ? part[t - d] : 0;
        __syncthreads();
        part[t] += u;
        __syncthreads();
    }
    if (t < N_SCAN_BLOCKS) bsum[t] = part[t] - v;  // exclusive
}

// Phase C: per-block exclusive scan + block offset; writes offsets and cursor
// (cursor doubles as the count input -> overwritten in place after load).
__global__ __launch_bounds__(SCAN_BLK) void k_scan_c(const int* __restrict__ bsum,
                                                     int* __restrict__ offsets,
                                                     int* __restrict__ cursor) {
    __shared__ int part[SCAN_BLK];
    const int i = blockIdx.x * SCAN_BLK + threadIdx.x;
    const int t = threadIdx.x;
    const int v = (i < N_NODES) ? cursor[i] : 0;
    part[t] = v;
    __syncthreads();
    for (int d = 1; d < SCAN_BLK; d <<= 1) {
        const int u = (t >= d) ? part[t - d] : 0;
        __syncthreads();
        part[t] += u;
        __syncthreads();
    }
    if (i < N_NODES) {
        const int off = bsum[blockIdx.x] + part[t] - v;
        offsets[i] = off;
        cursor[i]  = off;
    }
    if (i == 0) offsets[N_NODES] = N_EDGES;
}

__global__ __launch_bounds__(256) void k_scatter(const int* __restrict__ src,
                                                 const int* __restrict__ dst,
                                                 const int* __restrict__ et,
                                                 int* __restrict__ cursor,
                                                 unsigned* __restrict__ sorted) {
    const int e = blockIdx.x * 256 + threadIdx.x;
    if (e < N_EDGES) {
        const int pos = atomicAdd(&cursor[dst[e]], 1);
        sorted[pos] = (unsigned)src[e] | ((unsigned)et[e] << 17);  // src < 2^17, et < 64
    }
}

// ---------------------------------------------------------------- gather
// One 64-lane wave per dst node; lane = output feature.
__global__ __launch_bounds__(256) void k_gather(
    const int*      __restrict__ offsets,
    const unsigned* __restrict__ sorted,
    const float*    __restrict__ w_comp,   // (64, 2)
    const float*    __restrict__ hb2,      // (N, 64, 2)
    float*          __restrict__ out)      // (N, 64)
{
    const int lane = threadIdx.x & 63;
    int n = blockIdx.x * 4 + (threadIdx.x >> 6);
    if (n >= N_NODES) return;
    n = __builtin_amdgcn_readfirstlane(n);

    const int start = __builtin_amdgcn_readfirstlane(offsets[n]);
    const int end   = __builtin_amdgcn_readfirstlane(offsets[n + 1]);
    const float2* __restrict__ wc2  = (const float2*)w_comp;
    const float2* __restrict__ hb2v = (const float2*)hb2;

    float acc0 = 0.0f, acc1 = 0.0f;
    int k = start;
    for (; k + 3 < end; k += 4) {
        const unsigned p0 = sorted[k],     p1 = sorted[k + 1];
        const unsigned p2 = sorted[k + 2], p3 = sorted[k + 3];
        const float2 h0 = hb2v[(size_t)(p0 & 0x1FFFF) * 64 + lane];
        const float2 h1 = hb2v[(size_t)(p1 & 0x1FFFF) * 64 + lane];
        const float2 h2 = hb2v[(size_t)(p2 & 0x1FFFF) * 64 + lane];
        const float2 h3 = hb2v[(size_t)(p3 & 0x1FFFF) * 64 + lane];
        const float2 c0 = wc2[p0 >> 17], c1 = wc2[p1 >> 17];
        const float2 c2 = wc2[p2 >> 17], c3 = wc2[p3 >> 17];
        acc0 = fmaf(c0.x, h0.x, acc0); acc1 = fmaf(c0.y, h0.y, acc1);
        acc0 = fmaf(c1.x, h1.x, acc0); acc1 = fmaf(c1.y, h1.y, acc1);
        acc0 = fmaf(c2.x, h2.x, acc0); acc1 = fmaf(c2.y, h2.y, acc1);
        acc0 = fmaf(c3.x, h3.x, acc0); acc1 = fmaf(c3.y, h3.y, acc1);
    }
    for (; k < end; ++k) {
        const unsigned p0 = sorted[k];
        const float2 c0 = wc2[p0 >> 17];
        const float2 h0 = hb2v[(size_t)(p0 & 0x1FFFF) * 64 + lane];
        acc0 = fmaf(c0.x, h0.x, acc0);
        acc1 = fmaf(c0.y, h0.y, acc1);
    }
    out[(size_t)n * OUT_FEAT + lane] += acc0 + acc1;   // single writer, non-atomic
}

// ---------------------------------------------------------------- launch
extern "C" void kernel_launch(void* const* d_in, const int* in_sizes, int n_in,
                              void* d_out, int out_size, void* d_ws, size_t ws_size,
                              hipStream_t stream) {
    const float* feat        = (const float*)d_in[0];
    const float* weight      = (const float*)d_in[1];
    const float* w_comp      = (const float*)d_in[2];
    const float* loop_weight = (const float*)d_in[3];
    const float* h_bias      = (const float*)d_in[4];
    const int*   src         = (const int*)d_in[5];
    const int*   dst         = (const int*)d_in[6];
    const int*   etypes      = (const int*)d_in[7];
    float* out = (float*)d_out;

    // ws layout (4-byte units): hb2 | offsets | cursor | sorted | bsum
    float*    hb2     = (float*)d_ws;                       // 12,800,000 f32
    int*      offsets = (int*)d_ws + 12800000;              // 100,001 i32
    int*      cursor  = offsets + (N_NODES + 1);            // 100,000 i32
    unsigned* sorted  = (unsigned*)(cursor + N_NODES);      // 1,600,000 u32
    int*      bsum    = (int*)(sorted + N_EDGES);           // 512 i32

    hipMemsetAsync(cursor, 0, (size_t)N_NODES * sizeof(int), stream);
    k_hist<<<(N_EDGES + 255) / 256, 256, 0, stream>>>(dst, cursor);
    k_scan_a<<<N_SCAN_BLOCKS, SCAN_BLK, 0, stream>>>(cursor, bsum);
    k_scan_b<<<1, 512, 0, stream>>>(bsum);
    k_scan_c<<<N_SCAN_BLOCKS, SCAN_BLK, 0, stream>>>(bsum, offsets, cursor);
    k1_node_transform<<<2048, K1_COLS, 0, stream>>>(feat, weight, loop_weight, h_bias, hb2, out);
    k_scatter<<<(N_EDGES + 255) / 256, 256, 0, stream>>>(src, dst, etypes, cursor, sorted);
    k_gather<<<(N_NODES + 3) / 4, 256, 0, stream>>>(offsets, sorted, w_comp, hb2, out);
}